// Round 6
// baseline (406.783 us; speedup 1.0000x reference)
//
#include <hip/hip_runtime.h>
#include <hip/hip_bf16.h>
#include <stdint.h>

#define TS 524288u
#define TMASK (TS - 1u)
// dense quad tables for levels 0..4: sum of (NL[l]+1)^3 cells
#define QTOTAL 331757
#define NHL 11   // hashed levels 5..15

typedef __attribute__((ext_vector_type(8))) short bf16x8;
typedef __attribute__((ext_vector_type(4))) float f32x4;

__device__ __forceinline__ short f2bf(float f) {
    union { float f; uint32_t u; } v; v.f = f;
    const uint32_t r = (v.u + 0x7fffu + ((v.u >> 16) & 1u)) >> 16;  // RNE
    return (short)r;
}
// hardware RNE pack: 2 f32 -> 1 dword of 2 bf16 (identical rounding to f2bf)
__device__ __forceinline__ uint32_t cvtpk(float a, float b) {
    uint32_t r;
    asm("v_cvt_pk_bf16_f32 %0, %1, %2" : "=v"(r) : "v"(a), "v"(b));
    return r;
}
__device__ __forceinline__ short bf1(float a) { return (short)(cvtpk(a, a) & 0xffffu); }
__device__ __forceinline__ float bflo(uint32_t u) { return __uint_as_float(u << 16); }
__device__ __forceinline__ float bfhi(uint32_t u) { return __uint_as_float(u & 0xffff0000u); }
__device__ __forceinline__ uint32_t pack2(float a, float b) {
    return (uint32_t)(uint16_t)f2bf(a) | ((uint32_t)(uint16_t)f2bf(b) << 16);
}

__constant__ float c_NLf[16] = {16.f,22.f,30.f,42.f,58.f,80.f,111.f,153.f,
                                212.f,293.f,406.f,561.f,775.f,1071.f,1481.f,2046.f};
__constant__ int c_NP1[5]  = {17, 23, 31, 43, 59};
__constant__ int c_QOFF[5] = {0, 4913, 17080, 46871, 126378};

// ---------------------------------------------------------------------------
// K0: pack hashed-level tables (levels 5..15) f32 -> bf16 dwords.
// ---------------------------------------------------------------------------
__global__ __launch_bounds__(256)
void cvt_tables_h(const float2* __restrict__ src, uint32_t* __restrict__ dst, int npairs)
{
    const int i = blockIdx.x * 256 + threadIdx.x;
    if (i >= npairs) return;
    const float2 v = src[i];
    dst[i] = pack2(v.x, v.y);
}

// ---------------------------------------------------------------------------
// K0b: dense quad slabs for levels 0..4 built straight from the f32 tables.
// ---------------------------------------------------------------------------
__global__ __launch_bounds__(256)
void build_quad(const float2* __restrict__ tbf, uint4* __restrict__ quad)
{
    const int i = blockIdx.x * 256 + threadIdx.x;
    if (i >= QTOTAL) return;
    int l, base;
    if      (i <   4913) { l = 0; base = 0;      }
    else if (i <  17080) { l = 1; base = 4913;   }
    else if (i <  46871) { l = 2; base = 17080;  }
    else if (i < 126378) { l = 3; base = 46871;  }
    else                 { l = 4; base = 126378; }
    const int np1 = c_NP1[l];
    int r = i - base;
    const int z = r % np1; r /= np1;
    const int y = r % np1;
    const int x = r / np1;
    const float2* tb = tbf + (size_t)l * TS;
    const uint32_t hx  = (uint32_t)x;                       // PI1 = 1
    const uint32_t hy0 = (uint32_t)y       * 2654435761u;
    const uint32_t hy1 = (uint32_t)(y + 1) * 2654435761u;
    const uint32_t hz0 = (uint32_t)z       * 805459861u;
    const uint32_t hz1 = (uint32_t)(z + 1) * 805459861u;
    const float2 a = tb[(hx ^ hy0 ^ hz0) & TMASK];
    const float2 b = tb[(hx ^ hy0 ^ hz1) & TMASK];
    const float2 c = tb[(hx ^ hy1 ^ hz0) & TMASK];
    const float2 d = tb[(hx ^ hy1 ^ hz1) & TMASK];
    uint4 q;
    q.x = pack2(a.x, a.y);
    q.y = pack2(b.x, b.y);
    q.z = pack2(c.x, c.y);
    q.w = pack2(d.x, d.y);
    quad[i] = q;
}

// ---------------------------------------------------------------------------
// K0c: per-point prep. The un-fast-math "/3.0f" is a ~11-op IEEE divide; the
// R5 encode did 3 of them + 3 clamps PER POINT PER LEVEL (16x redundant,
// ~45 of ~145 VALU ops/pt-level -> VALUBusy 38.5%). Compute once, store the
// clamped coords; sx = -1 marks outside. Bit-identical values downstream.
// ---------------------------------------------------------------------------
__global__ __launch_bounds__(256)
void prep_pts(const float* __restrict__ xg, float* __restrict__ prep, int n)
{
    const int i = blockIdx.x * 256 + threadIdx.x;
    if (i >= n) return;
    const float sx = xg[3*i+0] / 3.0f;
    const float sy = xg[3*i+1] / 3.0f;
    const float sz = xg[3*i+2] / 3.0f;
    const bool inside = (fabsf(sx) < 0.5f) && (fabsf(sy) < 0.5f) && (fabsf(sz) < 0.5f);
    if (inside) {
        prep[3*i+0] = fminf(fmaxf(sx + 0.5f, 0.0f), 1.0f);
        prep[3*i+1] = fminf(fmaxf(sy + 0.5f, 0.0f), 1.0f);
        prep[3*i+2] = fminf(fmaxf(sz + 0.5f, 0.0f), 1.0f);
    } else {
        prep[3*i+0] = -1.0f;
        prep[3*i+1] = 0.0f;
        prep[3*i+2] = 0.0f;
    }
}

// ---------------------------------------------------------------------------
// K1: hash-grid encode, LEVEL-MAJOR block order (level = blockIdx / tiles):
// whole GPU sweeps one level at a time so each XCD's 4-MiB L2 holds that
// level's table -> gathers are L2 hits (R3: 174 us for all 16 levels).
// HASPREP variant reads the prepped clamped coords (no per-level div/clamp).
// Levels 0-4: quad slabs (2 tx/pt); levels 5-15: hashed, even-x pair trick.
// ---------------------------------------------------------------------------
__device__ __forceinline__ uint32_t enc_pt(const int l, const float sx, const float sy,
                                           const float sz,
                                           const uint32_t* __restrict__ tb16h,
                                           const uint4* __restrict__ qtab)
{
    const float nf = c_NLf[l];
    const float xn0 = sx * nf, xn1 = sy * nf, xn2 = sz * nf;
    const float fl0 = floorf(xn0), fl1 = floorf(xn1), fl2 = floorf(xn2);
    const float w0 = xn0 - fl0, w1 = xn1 - fl1, w2 = xn2 - fl2;
    const uint32_t f0 = (uint32_t)fl0, f1 = (uint32_t)fl1, f2 = (uint32_t)fl2;

    float v0x,v0y,v1x,v1y,v2x,v2y,v3x,v3y,v4x,v4y,v5x,v5y,v6x,v6y,v7x,v7y;

    if (l < 5) {
        const int np1 = c_NP1[l];
        const uint4* qt = qtab + c_QOFF[l];
        const int cell = ((int)f0 * np1 + (int)f1) * np1 + (int)f2;
        const uint4 qa = qt[cell];                    // x-layer f0
        const uint4 qb = qt[cell + np1 * np1];        // x-layer f0+1
        v0x = bflo(qa.x); v0y = bfhi(qa.x);   // (f0,f1,f2)
        v4x = bflo(qa.y); v4y = bfhi(qa.y);   // (f0,f1,c2)
        v2x = bflo(qa.z); v2y = bfhi(qa.z);   // (f0,c1,f2)
        v6x = bflo(qa.w); v6y = bfhi(qa.w);   // (f0,c1,c2)
        v1x = bflo(qb.x); v1y = bfhi(qb.x);   // (c0,f1,f2)
        v5x = bflo(qb.y); v5y = bfhi(qb.y);   // (c0,f1,c2)
        v3x = bflo(qb.z); v3y = bfhi(qb.z);   // (c0,c1,f2)
        v7x = bflo(qb.w); v7y = bfhi(qb.w);   // (c0,c1,c2)
    } else {
        const uint32_t c0 = (uint32_t)ceilf(xn0);
        const uint32_t c1 = (uint32_t)ceilf(xn1);
        const uint32_t c2 = (uint32_t)ceilf(xn2);
        const uint32_t hyf = f1 * 2654435761u, hyc = c1 * 2654435761u;
        const uint32_t hzf = f2 * 805459861u,  hzc = c2 * 805459861u;
        const uint32_t* tb = tb16h + (size_t)(l - 5) * TS;
        const uint32_t Sff = hyf ^ hzf, Scf = hyc ^ hzf;
        const uint32_t Sfc = hyf ^ hzc, Scc = hyc ^ hzc;
        uint32_t e0,e1,e2,e3,e4,e5,e6,e7;
        if ((f0 ^ c0) == 1u) {
            // f0 even, c0=f0+1: both x-corners live in one aligned 8-B slot
            const uint32_t h0 = (f0 ^ Sff) & TMASK;
            const uint32_t h2 = (f0 ^ Scf) & TMASK;
            const uint32_t h4 = (f0 ^ Sfc) & TMASK;
            const uint32_t h6 = (f0 ^ Scc) & TMASK;
            const uint2 t0 = *reinterpret_cast<const uint2*>(tb + (h0 & ~1u));
            const uint2 t2 = *reinterpret_cast<const uint2*>(tb + (h2 & ~1u));
            const uint2 t4 = *reinterpret_cast<const uint2*>(tb + (h4 & ~1u));
            const uint2 t6 = *reinterpret_cast<const uint2*>(tb + (h6 & ~1u));
            e0 = (h0 & 1u) ? t0.y : t0.x;  e1 = (h0 & 1u) ? t0.x : t0.y;
            e2 = (h2 & 1u) ? t2.y : t2.x;  e3 = (h2 & 1u) ? t2.x : t2.y;
            e4 = (h4 & 1u) ? t4.y : t4.x;  e5 = (h4 & 1u) ? t4.x : t4.y;
            e6 = (h6 & 1u) ? t6.y : t6.x;  e7 = (h6 & 1u) ? t6.x : t6.y;
        } else {
            e0 = tb[(f0 ^ Sff) & TMASK];  e1 = tb[(c0 ^ Sff) & TMASK];
            e2 = tb[(f0 ^ Scf) & TMASK];  e3 = tb[(c0 ^ Scf) & TMASK];
            e4 = tb[(f0 ^ Sfc) & TMASK];  e5 = tb[(c0 ^ Sfc) & TMASK];
            e6 = tb[(f0 ^ Scc) & TMASK];  e7 = tb[(c0 ^ Scc) & TMASK];
        }
        v0x = bflo(e0); v0y = bfhi(e0); v1x = bflo(e1); v1y = bfhi(e1);
        v2x = bflo(e2); v2y = bfhi(e2); v3x = bflo(e3); v3y = bfhi(e3);
        v4x = bflo(e4); v4y = bfhi(e4); v5x = bflo(e5); v5y = bfhi(e5);
        v6x = bflo(e6); v6y = bfhi(e6); v7x = bflo(e7); v7y = bfhi(e7);
    }

    // identical expression order to the passing kernel
    const float u0 = 1.0f - w0, u1 = 1.0f - w1, u2 = 1.0f - w2;
    float a0, a1;
    a0 = u0*u1*u2 * v0x;              a1 = u0*u1*u2 * v0y;
    a0 = fmaf(w0*u1*u2, v1x, a0);     a1 = fmaf(w0*u1*u2, v1y, a1);
    a0 = fmaf(u0*w1*u2, v2x, a0);     a1 = fmaf(u0*w1*u2, v2y, a1);
    a0 = fmaf(w0*w1*u2, v3x, a0);     a1 = fmaf(w0*w1*u2, v3y, a1);
    a0 = fmaf(u0*u1*w2, v4x, a0);     a1 = fmaf(u0*u1*w2, v4y, a1);
    a0 = fmaf(w0*u1*w2, v5x, a0);     a1 = fmaf(w0*u1*w2, v5y, a1);
    a0 = fmaf(u0*w1*w2, v6x, a0);     a1 = fmaf(u0*w1*w2, v6y, a1);
    a0 = fmaf(w0*w1*w2, v7x, a0);     a1 = fmaf(w0*w1*w2, v7y, a1);

    return cvtpk(a0, a1);
}

template<bool HASPREP>
__global__ __launch_bounds__(256)
void ngp_encode_lm(const float* __restrict__ xp, const uint32_t* __restrict__ tb16h,
                   const uint4* __restrict__ qtab, uint32_t* __restrict__ feats_lm,
                   const int n, const unsigned tiles)
{
    const unsigned b = blockIdx.x;
    const int l = (int)(b / tiles);
    const int p = (int)(b - (unsigned)l * tiles) * 256 + threadIdx.x;
    if (p >= n) return;

    if (HASPREP) {
        const float s0 = xp[3*p+0], s1 = xp[3*p+1], s2 = xp[3*p+2];
        if (s0 < 0.0f) { feats_lm[(size_t)l * n + p] = 0u; return; }
        feats_lm[(size_t)l * n + p] = enc_pt(l, s0, s1, s2, tb16h, qtab);
    } else {
        float sx = xp[3*p+0] / 3.0f, sy = xp[3*p+1] / 3.0f, sz = xp[3*p+2] / 3.0f;
        if (!((fabsf(sx) < 0.5f) && (fabsf(sy) < 0.5f) && (fabsf(sz) < 0.5f))) {
            feats_lm[(size_t)l * n + p] = 0u;
            return;
        }
        sx = fminf(fmaxf(sx + 0.5f, 0.0f), 1.0f);
        sy = fminf(fmaxf(sy + 0.5f, 0.0f), 1.0f);
        sz = fminf(fmaxf(sz + 0.5f, 0.0f), 1.0f);
        feats_lm[(size_t)l * n + p] = enc_pt(l, sx, sy, sz, tb16h, qtab);
    }
}

// fallback encode (no workspace for packed tables): f32 tables, level-major
__global__ __launch_bounds__(256)
void ngp_encode_f32(const float* __restrict__ xg, const float2* __restrict__ tbf,
                    uint32_t* __restrict__ feats_lm, const int n, const unsigned tiles)
{
    const unsigned b = blockIdx.x;
    const int l = (int)(b / tiles);
    const int p = (int)(b - (unsigned)l * tiles) * 256 + threadIdx.x;
    if (p >= n) return;
    float sx = xg[3*p+0] / 3.0f, sy = xg[3*p+1] / 3.0f, sz = xg[3*p+2] / 3.0f;
    if (!((fabsf(sx) < 0.5f) && (fabsf(sy) < 0.5f) && (fabsf(sz) < 0.5f))) {
        feats_lm[(size_t)l * n + p] = 0u;
        return;
    }
    sx = fminf(fmaxf(sx + 0.5f, 0.0f), 1.0f);
    sy = fminf(fmaxf(sy + 0.5f, 0.0f), 1.0f);
    sz = fminf(fmaxf(sz + 0.5f, 0.0f), 1.0f);
    const float nf = c_NLf[l];
    const float xn0 = sx*nf, xn1 = sy*nf, xn2 = sz*nf;
    const float fl0 = floorf(xn0), fl1 = floorf(xn1), fl2 = floorf(xn2);
    const float w0 = xn0-fl0, w1 = xn1-fl1, w2 = xn2-fl2;
    const uint32_t f0=(uint32_t)fl0, f1=(uint32_t)fl1, f2=(uint32_t)fl2;
    const uint32_t c0=(uint32_t)ceilf(xn0), c1=(uint32_t)ceilf(xn1), c2=(uint32_t)ceilf(xn2);
    const uint32_t hyf = f1*2654435761u, hyc = c1*2654435761u;
    const uint32_t hzf = f2*805459861u,  hzc = c2*805459861u;
    const float2* tb = tbf + (size_t)l * TS;
    const float2 e0 = tb[(f0^hyf^hzf)&TMASK], e1 = tb[(c0^hyf^hzf)&TMASK];
    const float2 e2 = tb[(f0^hyc^hzf)&TMASK], e3 = tb[(c0^hyc^hzf)&TMASK];
    const float2 e4 = tb[(f0^hyf^hzc)&TMASK], e5 = tb[(c0^hyf^hzc)&TMASK];
    const float2 e6 = tb[(f0^hyc^hzc)&TMASK], e7 = tb[(c0^hyc^hzc)&TMASK];
    const float u0 = 1.0f-w0, u1 = 1.0f-w1, u2 = 1.0f-w2;
    float a0, a1;
    a0 = u0*u1*u2 * e0.x;             a1 = u0*u1*u2 * e0.y;
    a0 = fmaf(w0*u1*u2, e1.x, a0);    a1 = fmaf(w0*u1*u2, e1.y, a1);
    a0 = fmaf(u0*w1*u2, e2.x, a0);    a1 = fmaf(u0*w1*u2, e2.y, a1);
    a0 = fmaf(w0*w1*u2, e3.x, a0);    a1 = fmaf(w0*w1*u2, e3.y, a1);
    a0 = fmaf(u0*u1*w2, e4.x, a0);    a1 = fmaf(u0*u1*w2, e4.y, a1);
    a0 = fmaf(w0*u1*w2, e5.x, a0);    a1 = fmaf(w0*u1*w2, e5.y, a1);
    a0 = fmaf(u0*w1*w2, e6.x, a0);    a1 = fmaf(u0*w1*w2, e6.y, a1);
    a0 = fmaf(w0*w1*w2, e7.x, a0);    a1 = fmaf(w0*w1*w2, e7.y, a1);
    feats_lm[(size_t)l * n + p] = pack2(a0, a1);
}

// ---------------------------------------------------------------------------
// K2: MFMA MLP. R5 lesson: weights-in-reg at 2 blk/CU was neutral vs LDS
// weights at 4 blk/CU -> split the difference: weights in registers (96 VGPR),
// biases back in LDS (-56 VGPR) => fits __launch_bounds__(256,3) = 3 blk/CU
// (+50% TLP vs R5). Inside mask comes from prep (1 load) instead of 3 x-loads
// + 3 IEEE divides per tile. ACT_STRIDE 72->76: 72's b128 reads fully stack
// 8 lanes on one 4-bank span; 76 is ~2-way (free). act is wave-private; no
// barriers in the tile loop; next-tile globals prefetched.
// ---------------------------------------------------------------------------
#define ACT_STRIDE 76

template<bool HASPREP>
__global__ __launch_bounds__(256, 3)
void ngp_mlp_mfma(const float* __restrict__ xp, const float* __restrict__ dg,
                  const uint32_t* __restrict__ feats_lm,
                  const float* __restrict__ dW1, const float* __restrict__ db1,
                  const float* __restrict__ dW2, const float* __restrict__ db2,
                  const float* __restrict__ cW1, const float* __restrict__ cb1,
                  const float* __restrict__ cW2, const float* __restrict__ cb2,
                  const float* __restrict__ cW3, const float* __restrict__ cb3,
                  float* __restrict__ out, int n)
{
    __shared__ __align__(16) short w1[2048];   // [jb4][lane64][e8]       L1: 32->64
    __shared__ __align__(16) short w2[1024];   // [kb2][lane64][e8]       L2: 64->16
    __shared__ __align__(16) short w3[4096];   // [jb4][kb2][lane64][e8]  L3: 64(pad43)->64
    __shared__ __align__(16) short w4[4096];   // [jb4][kb2][lane64][e8]  L4: 64->64
    __shared__ __align__(16) short w5[1024];   // [kb2][lane64][e8]       L5: 64->16(3 used)
    __shared__ __align__(16) float b1[64];
    __shared__ __align__(16) float b2[16];
    __shared__ __align__(16) float b3[64];
    __shared__ __align__(16) float b4[64];
    __shared__ __align__(16) float b5[16];
    __shared__ __align__(16) short act[4][16*ACT_STRIDE];   // one buffer per wave

    const int tid = threadIdx.x;

    // zero act once: guarantees stale bf16 reads (cin[43..63]) are finite
    for (int i2 = tid; i2 < 4*16*ACT_STRIDE/2; i2 += 256)
        reinterpret_cast<uint32_t*>(act)[i2] = 0u;

    for (int i2 = tid; i2 < 2048; i2 += 256) {
        const int jb = i2 >> 9, lane = (i2 >> 3) & 63, e = i2 & 7;
        const int j = jb*16 + (lane & 15), k = ((lane >> 4) << 3) + e;
        w1[i2] = f2bf(dW1[k*64 + j]);
    }
    for (int i2 = tid; i2 < 1024; i2 += 256) {
        const int kb = i2 >> 9, lane = (i2 >> 3) & 63, e = i2 & 7;
        const int j = lane & 15, k = kb*32 + ((lane >> 4) << 3) + e;
        w2[i2] = f2bf(dW2[k*16 + j]);
    }
    for (int i2 = tid; i2 < 4096; i2 += 256) {
        const int jb = i2 >> 10, kb = (i2 >> 9) & 1, lane = (i2 >> 3) & 63, e = i2 & 7;
        const int j = jb*16 + (lane & 15), k = kb*32 + ((lane >> 4) << 3) + e;
        w3[i2] = (k < 43) ? f2bf(cW1[k*64 + j]) : (short)0;
        w4[i2] = f2bf(cW2[k*64 + j]);
    }
    for (int i2 = tid; i2 < 1024; i2 += 256) {
        const int kb = i2 >> 9, lane = (i2 >> 3) & 63, e = i2 & 7;
        const int j = lane & 15, k = kb*32 + ((lane >> 4) << 3) + e;
        w5[i2] = (j < 3) ? f2bf(cW3[k*3 + j]) : (short)0;
    }
    if (tid < 64) { b1[tid] = db1[tid]; b3[tid] = cb1[tid]; b4[tid] = cb2[tid]; }
    if (tid < 16) { b2[tid] = db2[tid]; b5[tid] = (tid < 3) ? cb3[tid] : 0.0f; }
    __syncthreads();

    const int wv = tid >> 6, lane = tid & 63;
    const int p16 = lane & 15, quad = lane >> 4;
    const int dc = (quad < 3) ? quad : 0;       // direction component this lane owns
    short* buf = &act[wv][0];

    // ---- hoist loop-invariant WEIGHTS into registers (96 VGPR; biases stay LDS) ----
    bf16x8 A1[4], A2[2], A3[8], A4[8], A5[2];
    #pragma unroll
    for (int jb = 0; jb < 4; ++jb) A1[jb] = *reinterpret_cast<const bf16x8*>(&w1[(jb*64 + lane)*8]);
    #pragma unroll
    for (int kb = 0; kb < 2; ++kb) A2[kb] = *reinterpret_cast<const bf16x8*>(&w2[(kb*64 + lane)*8]);
    #pragma unroll
    for (int i = 0; i < 8; ++i) {
        A3[i] = *reinterpret_cast<const bf16x8*>(&w3[(i*64 + lane)*8]);
        A4[i] = *reinterpret_cast<const bf16x8*>(&w4[(i*64 + lane)*8]);
    }
    #pragma unroll
    for (int kb = 0; kb < 2; ++kb) A5[kb] = *reinterpret_cast<const bf16x8*>(&w5[(kb*64 + lane)*8]);

    const int ntiles = (n + 63) >> 6;   // 64 points per block-tile
    int t = blockIdx.x;
    if (t >= ntiles) return;

    // prefetch registers (next tile's data)
    int pp_n; bool valid_n;
    uint32_t fn0, fn1, fn2, fn3;
    float in0, in1, in2, dn;   // PREP: in0 = prep sx (sign = mask); else raw x

    auto issue = [&](int tt) {
        const int pr = tt*64 + wv*16 + p16;
        valid_n = (pr < n);
        pp_n = valid_n ? pr : (n - 1);
        fn0 = feats_lm[(size_t)(4*quad+0)*n + pp_n];
        fn1 = feats_lm[(size_t)(4*quad+1)*n + pp_n];
        fn2 = feats_lm[(size_t)(4*quad+2)*n + pp_n];
        fn3 = feats_lm[(size_t)(4*quad+3)*n + pp_n];
        if (HASPREP) {
            in0 = xp[3*pp_n];                 // sx >= 0 iff inside
        } else {
            in0 = xp[3*pp_n+0];
            in1 = xp[3*pp_n+1];
            in2 = xp[3*pp_n+2];
        }
        dn  = dg[3*pp_n + dc];
    };

    issue(t);
    while (t < ntiles) {
        // consume prefetched tile
        const int pp = pp_n;
        const bool valid = valid_n;
        const uint32_t fc0 = fn0, fc1 = fn1, fc2 = fn2, fc3 = fn3;
        const float ic0 = in0, ic1 = in1, ic2 = in2;
        const float dv = dn;

        // issue next tile's loads (independent of this tile's compute)
        const int t2 = t + gridDim.x;
        if (t2 < ntiles) issue(t2);

        bool inside;
        if (HASPREP) {
            inside = (ic0 >= 0.0f);
        } else {
            inside = (fabsf(ic0 / 3.0f) < 0.5f) && (fabsf(ic1 / 3.0f) < 0.5f)
                  && (fabsf(ic2 / 3.0f) < 0.5f);
        }

        // ---- L1: feats[32] -> hid[64], relu ----
        union { int4 i; bf16x8 v; } bu;
        bu.i.x = (int)fc0; bu.i.y = (int)fc1; bu.i.z = (int)fc2; bu.i.w = (int)fc3;
        const bf16x8 bA = bu.v;
        #pragma unroll
        for (int jb = 0; jb < 4; ++jb) {
            const int j0 = jb*16 + quad*4;
            f32x4 acc = *reinterpret_cast<const f32x4*>(&b1[j0]);
            acc = __builtin_amdgcn_mfma_f32_16x16x32_bf16(A1[jb], bA, acc, 0, 0, 0);
            uint2 s;
            s.x = cvtpk(fmaxf(acc[0], 0.f), fmaxf(acc[1], 0.f));
            s.y = cvtpk(fmaxf(acc[2], 0.f), fmaxf(acc[3], 0.f));
            *reinterpret_cast<uint2*>(&buf[p16*ACT_STRIDE + j0]) = s;
        }

        // ---- L2: hid[64] -> h16[16] (no relu); reads hoisted before writes ----
        {
            const bf16x8 bF0 = *reinterpret_cast<const bf16x8*>(&buf[p16*ACT_STRIDE + quad*8]);
            const bf16x8 bF1 = *reinterpret_cast<const bf16x8*>(&buf[p16*ACT_STRIDE + 32 + quad*8]);
            f32x4 acc2 = *reinterpret_cast<const f32x4*>(&b2[quad*4]);
            acc2 = __builtin_amdgcn_mfma_f32_16x16x32_bf16(A2[0], bF0, acc2, 0, 0, 0);
            acc2 = __builtin_amdgcn_mfma_f32_16x16x32_bf16(A2[1], bF1, acc2, 0, 0, 0);
            if (quad == 0 && valid)
                out[(size_t)3*n + pp] = inside ? __expf(acc2[0]) : 0.0f;
            uint2 s;
            s.x = cvtpk(acc2[0], acc2[1]);
            s.y = cvtpk(acc2[2], acc2[3]);
            *reinterpret_cast<uint2*>(&buf[p16*ACT_STRIDE + quad*4]) = s;
        }
        // pos-enc -> buf[p][16..42]; [43..63] stays stale-finite (w3 zeros cover it)
        if (quad < 3) {
            buf[p16*ACT_STRIDE + 16 + quad] = bf1(dv);
            float arg = dv;
            #pragma unroll
            for (int f = 0; f < 4; ++f) {
                buf[p16*ACT_STRIDE + 19 + 6*f + quad] = bf1(__sinf(arg));
                buf[p16*ACT_STRIDE + 22 + 6*f + quad] = bf1(__cosf(arg));
                arg += arg;    // exact *2
            }
        }

        // ---- L3: cin[64(pad)] -> c1[64], relu ----
        {
            const bf16x8 bF0 = *reinterpret_cast<const bf16x8*>(&buf[p16*ACT_STRIDE + quad*8]);
            const bf16x8 bF1 = *reinterpret_cast<const bf16x8*>(&buf[p16*ACT_STRIDE + 32 + quad*8]);
            #pragma unroll
            for (int jb = 0; jb < 4; ++jb) {
                const int j0 = jb*16 + quad*4;
                f32x4 acc = *reinterpret_cast<const f32x4*>(&b3[j0]);
                acc = __builtin_amdgcn_mfma_f32_16x16x32_bf16(A3[jb*2 + 0], bF0, acc, 0, 0, 0);
                acc = __builtin_amdgcn_mfma_f32_16x16x32_bf16(A3[jb*2 + 1], bF1, acc, 0, 0, 0);
                uint2 s;
                s.x = cvtpk(fmaxf(acc[0], 0.f), fmaxf(acc[1], 0.f));
                s.y = cvtpk(fmaxf(acc[2], 0.f), fmaxf(acc[3], 0.f));
                *reinterpret_cast<uint2*>(&buf[p16*ACT_STRIDE + j0]) = s;
            }
        }

        // ---- L4: c1[64] -> c2[64], relu ----
        {
            const bf16x8 bF0 = *reinterpret_cast<const bf16x8*>(&buf[p16*ACT_STRIDE + quad*8]);
            const bf16x8 bF1 = *reinterpret_cast<const bf16x8*>(&buf[p16*ACT_STRIDE + 32 + quad*8]);
            #pragma unroll
            for (int jb = 0; jb < 4; ++jb) {
                const int j0 = jb*16 + quad*4;
                f32x4 acc = *reinterpret_cast<const f32x4*>(&b4[j0]);
                acc = __builtin_amdgcn_mfma_f32_16x16x32_bf16(A4[jb*2 + 0], bF0, acc, 0, 0, 0);
                acc = __builtin_amdgcn_mfma_f32_16x16x32_bf16(A4[jb*2 + 1], bF1, acc, 0, 0, 0);
                uint2 s;
                s.x = cvtpk(fmaxf(acc[0], 0.f), fmaxf(acc[1], 0.f));
                s.y = cvtpk(fmaxf(acc[2], 0.f), fmaxf(acc[3], 0.f));
                *reinterpret_cast<uint2*>(&buf[p16*ACT_STRIDE + j0]) = s;
            }
        }

        // ---- L5: c2[64] -> 16 (3 used), sigmoid, masked store ----
        {
            const bf16x8 bF0 = *reinterpret_cast<const bf16x8*>(&buf[p16*ACT_STRIDE + quad*8]);
            const bf16x8 bF1 = *reinterpret_cast<const bf16x8*>(&buf[p16*ACT_STRIDE + 32 + quad*8]);
            f32x4 acc5 = *reinterpret_cast<const f32x4*>(&b5[quad*4]);
            acc5 = __builtin_amdgcn_mfma_f32_16x16x32_bf16(A5[0], bF0, acc5, 0, 0, 0);
            acc5 = __builtin_amdgcn_mfma_f32_16x16x32_bf16(A5[1], bF1, acc5, 0, 0, 0);
            if (quad == 0 && valid) {
                #pragma unroll
                for (int r = 0; r < 3; ++r) {
                    const float s = 1.0f / (1.0f + __expf(-acc5[r]));
                    out[3*(size_t)pp + r] = inside ? s : 0.0f;
                }
            }
        }
        t = t2;
        // no barrier: act is wave-private; in-wave LDS ordering protects reuse
    }
}

extern "C" void kernel_launch(void* const* d_in, const int* in_sizes, int n_in,
                              void* d_out, int out_size, void* d_ws, size_t ws_size,
                              hipStream_t stream)
{
    const float* x   = (const float*)d_in[0];
    const float* d   = (const float*)d_in[1];
    const float* tb  = (const float*)d_in[2];
    const float* dW1 = (const float*)d_in[3];
    const float* db1 = (const float*)d_in[4];
    const float* dW2 = (const float*)d_in[5];
    const float* db2 = (const float*)d_in[6];
    const float* cW1 = (const float*)d_in[7];
    const float* cb1 = (const float*)d_in[8];
    const float* cW2 = (const float*)d_in[9];
    const float* cb2 = (const float*)d_in[10];
    const float* cW3 = (const float*)d_in[11];
    const float* cb3 = (const float*)d_in[12];
    float* out = (float*)d_out;

    const int n = in_sizes[0] / 3;              // N_PTS = 1M

    size_t off = 0;
    uint32_t* feats_lm = (uint32_t*)d_ws;                 off += (size_t)n * 16 * 4;
    uint32_t* tb16h    = (uint32_t*)((char*)d_ws + off);  off += (size_t)NHL * TS * 4;
    uint4*    quadbuf  = (uint4*)((char*)d_ws + off);     off += (size_t)QTOTAL * 16;
    const size_t off1 = off;
    float*    prepbuf  = (float*)((char*)d_ws + off);     off += (size_t)n * 3 * 4;
    const size_t off2 = off;
    const bool planA  = (ws_size >= off1);
    const bool planA2 = (ws_size >= off2);

    const unsigned tiles = (unsigned)((n + 255) / 256);
    const int ntiles = (n + 63) >> 6;
    const int nblk = (ntiles < 768) ? ntiles : 768;       // 3 blocks/CU

    if (planA) {
        {
            const int npairs = NHL * (int)TS;
            hipLaunchKernelGGL(cvt_tables_h, dim3((npairs + 255) / 256), dim3(256), 0, stream,
                               (const float2*)tb + 5 * (size_t)TS, tb16h, npairs);
        }
        hipLaunchKernelGGL(build_quad, dim3((QTOTAL + 255) / 256), dim3(256), 0, stream,
                           (const float2*)tb, quadbuf);
        if (planA2) {
            hipLaunchKernelGGL(prep_pts, dim3((n + 255) / 256), dim3(256), 0, stream,
                               x, prepbuf, n);
            hipLaunchKernelGGL((ngp_encode_lm<true>), dim3(tiles * 16), dim3(256), 0, stream,
                               prepbuf, tb16h, quadbuf, feats_lm, n, tiles);
            hipLaunchKernelGGL((ngp_mlp_mfma<true>), dim3(nblk), dim3(256), 0, stream,
                               prepbuf, d, feats_lm, dW1, db1, dW2, db2,
                               cW1, cb1, cW2, cb2, cW3, cb3, out, n);
        } else {
            hipLaunchKernelGGL((ngp_encode_lm<false>), dim3(tiles * 16), dim3(256), 0, stream,
                               x, tb16h, quadbuf, feats_lm, n, tiles);
            hipLaunchKernelGGL((ngp_mlp_mfma<false>), dim3(nblk), dim3(256), 0, stream,
                               x, d, feats_lm, dW1, db1, dW2, db2,
                               cW1, cb1, cW2, cb2, cW3, cb3, out, n);
        }
    } else {
        hipLaunchKernelGGL(ngp_encode_f32, dim3(tiles * 16), dim3(256), 0, stream,
                           x, (const float2*)tb, feats_lm, n, tiles);
        hipLaunchKernelGGL((ngp_mlp_mfma<false>), dim3(nblk), dim3(256), 0, stream,
                           x, d, feats_lm, dW1, db1, dW2, db2,
                           cW1, cb1, cW2, cb2, cW3, cb3, out, n);
    }
}

// Round 7
// 366.407 us; speedup vs baseline: 1.1102x; 1.1102x over previous
//
#include <hip/hip_runtime.h>
#include <hip/hip_bf16.h>
#include <stdint.h>

#define TS 524288u
#define TMASK (TS - 1u)
// dense quad tables for levels 0..4: sum of (NL[l]+1)^3 cells
#define QTOTAL 331757
#define NHL 11   // hashed levels 5..15

typedef __attribute__((ext_vector_type(8))) short bf16x8;
typedef __attribute__((ext_vector_type(4))) float f32x4;

__device__ __forceinline__ short f2bf(float f) {
    union { float f; uint32_t u; } v; v.f = f;
    const uint32_t r = (v.u + 0x7fffu + ((v.u >> 16) & 1u)) >> 16;  // RNE
    return (short)r;
}
// hardware RNE pack: 2 f32 -> 1 dword of 2 bf16 (identical rounding to f2bf)
__device__ __forceinline__ uint32_t cvtpk(float a, float b) {
    uint32_t r;
    asm("v_cvt_pk_bf16_f32 %0, %1, %2" : "=v"(r) : "v"(a), "v"(b));
    return r;
}
__device__ __forceinline__ short bf1(float a) { return (short)(cvtpk(a, a) & 0xffffu); }
__device__ __forceinline__ float bflo(uint32_t u) { return __uint_as_float(u << 16); }
__device__ __forceinline__ float bfhi(uint32_t u) { return __uint_as_float(u & 0xffff0000u); }
__device__ __forceinline__ uint32_t pack2(float a, float b) {
    return (uint32_t)(uint16_t)f2bf(a) | ((uint32_t)(uint16_t)f2bf(b) << 16);
}

__constant__ float c_NLf[16] = {16.f,22.f,30.f,42.f,58.f,80.f,111.f,153.f,
                                212.f,293.f,406.f,561.f,775.f,1071.f,1481.f,2046.f};
__constant__ int c_NP1[5]  = {17, 23, 31, 43, 59};
__constant__ int c_QOFF[5] = {0, 4913, 17080, 46871, 126378};

// ---------------------------------------------------------------------------
// K0: pack hashed-level tables (levels 5..15) f32 -> bf16 dwords.
// ---------------------------------------------------------------------------
__global__ __launch_bounds__(256)
void cvt_tables_h(const float2* __restrict__ src, uint32_t* __restrict__ dst, int npairs)
{
    const int i = blockIdx.x * 256 + threadIdx.x;
    if (i >= npairs) return;
    const float2 v = src[i];
    dst[i] = pack2(v.x, v.y);
}

// ---------------------------------------------------------------------------
// K0b: dense quad slabs for levels 0..4 built straight from the f32 tables.
// ---------------------------------------------------------------------------
__global__ __launch_bounds__(256)
void build_quad(const float2* __restrict__ tbf, uint4* __restrict__ quad)
{
    const int i = blockIdx.x * 256 + threadIdx.x;
    if (i >= QTOTAL) return;
    int l, base;
    if      (i <   4913) { l = 0; base = 0;      }
    else if (i <  17080) { l = 1; base = 4913;   }
    else if (i <  46871) { l = 2; base = 17080;  }
    else if (i < 126378) { l = 3; base = 46871;  }
    else                 { l = 4; base = 126378; }
    const int np1 = c_NP1[l];
    int r = i - base;
    const int z = r % np1; r /= np1;
    const int y = r % np1;
    const int x = r / np1;
    const float2* tb = tbf + (size_t)l * TS;
    const uint32_t hx  = (uint32_t)x;                       // PI1 = 1
    const uint32_t hy0 = (uint32_t)y       * 2654435761u;
    const uint32_t hy1 = (uint32_t)(y + 1) * 2654435761u;
    const uint32_t hz0 = (uint32_t)z       * 805459861u;
    const uint32_t hz1 = (uint32_t)(z + 1) * 805459861u;
    const float2 a = tb[(hx ^ hy0 ^ hz0) & TMASK];
    const float2 b = tb[(hx ^ hy0 ^ hz1) & TMASK];
    const float2 c = tb[(hx ^ hy1 ^ hz0) & TMASK];
    const float2 d = tb[(hx ^ hy1 ^ hz1) & TMASK];
    uint4 q;
    q.x = pack2(a.x, a.y);
    q.y = pack2(b.x, b.y);
    q.z = pack2(c.x, c.y);
    q.w = pack2(d.x, d.y);
    quad[i] = q;
}

// ---------------------------------------------------------------------------
// K1: hash-grid encode, LEVEL-MAJOR block order (level = blockIdx / tiles):
// whole GPU sweeps one level at a time so each XCD's 4-MiB L2 holds that
// level's table -> gathers are L2 hits (R3/R5: 173 us for all 16 levels).
// NEW (R7): feats writes are NON-TEMPORAL. feats (64 MB) is write-once/
// read-much-later; normal write-allocate traffic was evicting the 12-MB x
// array from L3 between level passes (FETCH showed 16 x 12 MB re-read from
// HBM). nt stores keep x L3-resident across all 16 passes.
// Levels 0-4: quad slabs (2 tx/pt); levels 5-15: hashed, even-x pair trick.
// ---------------------------------------------------------------------------
__device__ __forceinline__ uint32_t enc_pt(const int l, const float sx, const float sy,
                                           const float sz,
                                           const uint32_t* __restrict__ tb16h,
                                           const uint4* __restrict__ qtab)
{
    const float nf = c_NLf[l];
    const float xn0 = sx * nf, xn1 = sy * nf, xn2 = sz * nf;
    const float fl0 = floorf(xn0), fl1 = floorf(xn1), fl2 = floorf(xn2);
    const float w0 = xn0 - fl0, w1 = xn1 - fl1, w2 = xn2 - fl2;
    const uint32_t f0 = (uint32_t)fl0, f1 = (uint32_t)fl1, f2 = (uint32_t)fl2;

    float v0x,v0y,v1x,v1y,v2x,v2y,v3x,v3y,v4x,v4y,v5x,v5y,v6x,v6y,v7x,v7y;

    if (l < 5) {
        const int np1 = c_NP1[l];
        const uint4* qt = qtab + c_QOFF[l];
        const int cell = ((int)f0 * np1 + (int)f1) * np1 + (int)f2;
        const uint4 qa = qt[cell];                    // x-layer f0
        const uint4 qb = qt[cell + np1 * np1];        // x-layer f0+1
        v0x = bflo(qa.x); v0y = bfhi(qa.x);   // (f0,f1,f2)
        v4x = bflo(qa.y); v4y = bfhi(qa.y);   // (f0,f1,c2)
        v2x = bflo(qa.z); v2y = bfhi(qa.z);   // (f0,c1,f2)
        v6x = bflo(qa.w); v6y = bfhi(qa.w);   // (f0,c1,c2)
        v1x = bflo(qb.x); v1y = bfhi(qb.x);   // (c0,f1,f2)
        v5x = bflo(qb.y); v5y = bfhi(qb.y);   // (c0,f1,c2)
        v3x = bflo(qb.z); v3y = bfhi(qb.z);   // (c0,c1,f2)
        v7x = bflo(qb.w); v7y = bfhi(qb.w);   // (c0,c1,c2)
    } else {
        const uint32_t c0 = (uint32_t)ceilf(xn0);
        const uint32_t c1 = (uint32_t)ceilf(xn1);
        const uint32_t c2 = (uint32_t)ceilf(xn2);
        const uint32_t hyf = f1 * 2654435761u, hyc = c1 * 2654435761u;
        const uint32_t hzf = f2 * 805459861u,  hzc = c2 * 805459861u;
        const uint32_t* tb = tb16h + (size_t)(l - 5) * TS;
        const uint32_t Sff = hyf ^ hzf, Scf = hyc ^ hzf;
        const uint32_t Sfc = hyf ^ hzc, Scc = hyc ^ hzc;
        uint32_t e0,e1,e2,e3,e4,e5,e6,e7;
        if ((f0 ^ c0) == 1u) {
            // f0 even, c0=f0+1: both x-corners live in one aligned 8-B slot
            const uint32_t h0 = (f0 ^ Sff) & TMASK;
            const uint32_t h2 = (f0 ^ Scf) & TMASK;
            const uint32_t h4 = (f0 ^ Sfc) & TMASK;
            const uint32_t h6 = (f0 ^ Scc) & TMASK;
            const uint2 t0 = *reinterpret_cast<const uint2*>(tb + (h0 & ~1u));
            const uint2 t2 = *reinterpret_cast<const uint2*>(tb + (h2 & ~1u));
            const uint2 t4 = *reinterpret_cast<const uint2*>(tb + (h4 & ~1u));
            const uint2 t6 = *reinterpret_cast<const uint2*>(tb + (h6 & ~1u));
            e0 = (h0 & 1u) ? t0.y : t0.x;  e1 = (h0 & 1u) ? t0.x : t0.y;
            e2 = (h2 & 1u) ? t2.y : t2.x;  e3 = (h2 & 1u) ? t2.x : t2.y;
            e4 = (h4 & 1u) ? t4.y : t4.x;  e5 = (h4 & 1u) ? t4.x : t4.y;
            e6 = (h6 & 1u) ? t6.y : t6.x;  e7 = (h6 & 1u) ? t6.x : t6.y;
        } else {
            e0 = tb[(f0 ^ Sff) & TMASK];  e1 = tb[(c0 ^ Sff) & TMASK];
            e2 = tb[(f0 ^ Scf) & TMASK];  e3 = tb[(c0 ^ Scf) & TMASK];
            e4 = tb[(f0 ^ Sfc) & TMASK];  e5 = tb[(c0 ^ Sfc) & TMASK];
            e6 = tb[(f0 ^ Scc) & TMASK];  e7 = tb[(c0 ^ Scc) & TMASK];
        }
        v0x = bflo(e0); v0y = bfhi(e0); v1x = bflo(e1); v1y = bfhi(e1);
        v2x = bflo(e2); v2y = bfhi(e2); v3x = bflo(e3); v3y = bfhi(e3);
        v4x = bflo(e4); v4y = bfhi(e4); v5x = bflo(e5); v5y = bfhi(e5);
        v6x = bflo(e6); v6y = bfhi(e6); v7x = bflo(e7); v7y = bfhi(e7);
    }

    // identical expression order to the passing kernel
    const float u0 = 1.0f - w0, u1 = 1.0f - w1, u2 = 1.0f - w2;
    float a0, a1;
    a0 = u0*u1*u2 * v0x;              a1 = u0*u1*u2 * v0y;
    a0 = fmaf(w0*u1*u2, v1x, a0);     a1 = fmaf(w0*u1*u2, v1y, a1);
    a0 = fmaf(u0*w1*u2, v2x, a0);     a1 = fmaf(u0*w1*u2, v2y, a1);
    a0 = fmaf(w0*w1*u2, v3x, a0);     a1 = fmaf(w0*w1*u2, v3y, a1);
    a0 = fmaf(u0*u1*w2, v4x, a0);     a1 = fmaf(u0*u1*w2, v4y, a1);
    a0 = fmaf(w0*u1*w2, v5x, a0);     a1 = fmaf(w0*u1*w2, v5y, a1);
    a0 = fmaf(u0*w1*w2, v6x, a0);     a1 = fmaf(u0*w1*w2, v6y, a1);
    a0 = fmaf(w0*w1*w2, v7x, a0);     a1 = fmaf(w0*w1*w2, v7y, a1);

    return cvtpk(a0, a1);
}

__global__ __launch_bounds__(256)
void ngp_encode_lm(const float* __restrict__ xg, const uint32_t* __restrict__ tb16h,
                   const uint4* __restrict__ qtab, uint32_t* __restrict__ feats_lm,
                   const int n, const unsigned tiles)
{
    const unsigned b = blockIdx.x;
    const int l = (int)(b / tiles);
    const int p = (int)(b - (unsigned)l * tiles) * 256 + threadIdx.x;
    if (p >= n) return;

    float sx = xg[3*p+0] / 3.0f, sy = xg[3*p+1] / 3.0f, sz = xg[3*p+2] / 3.0f;
    if (!((fabsf(sx) < 0.5f) && (fabsf(sy) < 0.5f) && (fabsf(sz) < 0.5f))) {
        __builtin_nontemporal_store(0u, &feats_lm[(size_t)l * n + p]);
        return;
    }
    sx = fminf(fmaxf(sx + 0.5f, 0.0f), 1.0f);
    sy = fminf(fmaxf(sy + 0.5f, 0.0f), 1.0f);
    sz = fminf(fmaxf(sz + 0.5f, 0.0f), 1.0f);
    const uint32_t fv = enc_pt(l, sx, sy, sz, tb16h, qtab);
    __builtin_nontemporal_store(fv, &feats_lm[(size_t)l * n + p]);
}

// fallback encode (no workspace for packed tables): f32 tables, level-major
__global__ __launch_bounds__(256)
void ngp_encode_f32(const float* __restrict__ xg, const float2* __restrict__ tbf,
                    uint32_t* __restrict__ feats_lm, const int n, const unsigned tiles)
{
    const unsigned b = blockIdx.x;
    const int l = (int)(b / tiles);
    const int p = (int)(b - (unsigned)l * tiles) * 256 + threadIdx.x;
    if (p >= n) return;
    float sx = xg[3*p+0] / 3.0f, sy = xg[3*p+1] / 3.0f, sz = xg[3*p+2] / 3.0f;
    if (!((fabsf(sx) < 0.5f) && (fabsf(sy) < 0.5f) && (fabsf(sz) < 0.5f))) {
        feats_lm[(size_t)l * n + p] = 0u;
        return;
    }
    sx = fminf(fmaxf(sx + 0.5f, 0.0f), 1.0f);
    sy = fminf(fmaxf(sy + 0.5f, 0.0f), 1.0f);
    sz = fminf(fmaxf(sz + 0.5f, 0.0f), 1.0f);
    const float nf = c_NLf[l];
    const float xn0 = sx*nf, xn1 = sy*nf, xn2 = sz*nf;
    const float fl0 = floorf(xn0), fl1 = floorf(xn1), fl2 = floorf(xn2);
    const float w0 = xn0-fl0, w1 = xn1-fl1, w2 = xn2-fl2;
    const uint32_t f0=(uint32_t)fl0, f1=(uint32_t)fl1, f2=(uint32_t)fl2;
    const uint32_t c0=(uint32_t)ceilf(xn0), c1=(uint32_t)ceilf(xn1), c2=(uint32_t)ceilf(xn2);
    const uint32_t hyf = f1*2654435761u, hyc = c1*2654435761u;
    const uint32_t hzf = f2*805459861u,  hzc = c2*805459861u;
    const float2* tb = tbf + (size_t)l * TS;
    const float2 e0 = tb[(f0^hyf^hzf)&TMASK], e1 = tb[(c0^hyf^hzf)&TMASK];
    const float2 e2 = tb[(f0^hyc^hzf)&TMASK], e3 = tb[(c0^hyc^hzf)&TMASK];
    const float2 e4 = tb[(f0^hyf^hzc)&TMASK], e5 = tb[(c0^hyf^hzc)&TMASK];
    const float2 e6 = tb[(f0^hyc^hzc)&TMASK], e7 = tb[(c0^hyc^hzc)&TMASK];
    const float u0 = 1.0f-w0, u1 = 1.0f-w1, u2 = 1.0f-w2;
    float a0, a1;
    a0 = u0*u1*u2 * e0.x;             a1 = u0*u1*u2 * e0.y;
    a0 = fmaf(w0*u1*u2, e1.x, a0);    a1 = fmaf(w0*u1*u2, e1.y, a1);
    a0 = fmaf(u0*w1*u2, e2.x, a0);    a1 = fmaf(u0*w1*u2, e2.y, a1);
    a0 = fmaf(w0*w1*u2, e3.x, a0);    a1 = fmaf(w0*w1*u2, e3.y, a1);
    a0 = fmaf(u0*u1*w2, e4.x, a0);    a1 = fmaf(u0*u1*w2, e4.y, a1);
    a0 = fmaf(w0*u1*w2, e5.x, a0);    a1 = fmaf(w0*u1*w2, e5.y, a1);
    a0 = fmaf(u0*w1*w2, e6.x, a0);    a1 = fmaf(u0*w1*w2, e6.y, a1);
    a0 = fmaf(w0*w1*w2, e7.x, a0);    a1 = fmaf(w0*w1*w2, e7.y, a1);
    feats_lm[(size_t)l * n + p] = pack2(a0, a1);
}

// ---------------------------------------------------------------------------
// K2: MFMA MLP, TWO INDEPENDENT POINT-GROUPS PER WAVE (32 pts/wave-tile).
// R3-R6 showed the MLP pinned ~3x above its VALU+MFMA floor across four
// variants -> the serial per-tile chain (5x MFMA->cvt->ds_write->ds_read) is
// the limiter. Group A (rows 0-15) and group B (rows 16-31) give every layer
// two independent chains -> chain ILP x2. Weights in registers (96 VGPR,
// proven R5), biases in LDS, ACT_STRIDE back to 72 (76 broke the 16-B
// alignment of ds_read_b128: 152 mod 16 = 8 -> split reads, R6 regression).
// __launch_bounds__(256,2) (R6's (256,3) forced ~170-VGPR cap -> spills).
// act is wave-private; no barriers in the tile loop; next tile prefetched.
// ---------------------------------------------------------------------------
#define ACT_STRIDE 72

__global__ __launch_bounds__(256, 2)
void ngp_mlp_mfma(const float* __restrict__ xg, const float* __restrict__ dg,
                  const uint32_t* __restrict__ feats_lm,
                  const float* __restrict__ dW1, const float* __restrict__ db1,
                  const float* __restrict__ dW2, const float* __restrict__ db2,
                  const float* __restrict__ cW1, const float* __restrict__ cb1,
                  const float* __restrict__ cW2, const float* __restrict__ cb2,
                  const float* __restrict__ cW3, const float* __restrict__ cb3,
                  float* __restrict__ out, int n)
{
    __shared__ __align__(16) short w1[2048];
    __shared__ __align__(16) short w2[1024];
    __shared__ __align__(16) short w3[4096];
    __shared__ __align__(16) short w4[4096];
    __shared__ __align__(16) short w5[1024];
    __shared__ __align__(16) float b1[64];
    __shared__ __align__(16) float b2[16];
    __shared__ __align__(16) float b3[64];
    __shared__ __align__(16) float b4[64];
    __shared__ __align__(16) float b5[16];
    __shared__ __align__(16) short act[4][32*ACT_STRIDE];   // 32 rows per wave (A:0-15, B:16-31)

    const int tid = threadIdx.x;

    // zero act once: guarantees stale bf16 reads (cin[43..63]) are finite
    for (int i2 = tid; i2 < 4*32*ACT_STRIDE/2; i2 += 256)
        reinterpret_cast<uint32_t*>(act)[i2] = 0u;

    for (int i2 = tid; i2 < 2048; i2 += 256) {
        const int jb = i2 >> 9, lane = (i2 >> 3) & 63, e = i2 & 7;
        const int j = jb*16 + (lane & 15), k = ((lane >> 4) << 3) + e;
        w1[i2] = f2bf(dW1[k*64 + j]);
    }
    for (int i2 = tid; i2 < 1024; i2 += 256) {
        const int kb = i2 >> 9, lane = (i2 >> 3) & 63, e = i2 & 7;
        const int j = lane & 15, k = kb*32 + ((lane >> 4) << 3) + e;
        w2[i2] = f2bf(dW2[k*16 + j]);
    }
    for (int i2 = tid; i2 < 4096; i2 += 256) {
        const int jb = i2 >> 10, kb = (i2 >> 9) & 1, lane = (i2 >> 3) & 63, e = i2 & 7;
        const int j = jb*16 + (lane & 15), k = kb*32 + ((lane >> 4) << 3) + e;
        w3[i2] = (k < 43) ? f2bf(cW1[k*64 + j]) : (short)0;
        w4[i2] = f2bf(cW2[k*64 + j]);
    }
    for (int i2 = tid; i2 < 1024; i2 += 256) {
        const int kb = i2 >> 9, lane = (i2 >> 3) & 63, e = i2 & 7;
        const int j = lane & 15, k = kb*32 + ((lane >> 4) << 3) + e;
        w5[i2] = (j < 3) ? f2bf(cW3[k*3 + j]) : (short)0;
    }
    if (tid < 64) { b1[tid] = db1[tid]; b3[tid] = cb1[tid]; b4[tid] = cb2[tid]; }
    if (tid < 16) { b2[tid] = db2[tid]; b5[tid] = (tid < 3) ? cb3[tid] : 0.0f; }
    __syncthreads();

    const int wv = tid >> 6, lane = tid & 63;
    const int p16 = lane & 15, quad = lane >> 4;
    const int dc = (quad < 3) ? quad : 0;       // direction component this lane owns
    short* bufA = &act[wv][0];                   // rows 0-15
    short* bufB = &act[wv][16*ACT_STRIDE];       // rows 16-31

    // ---- hoist loop-invariant WEIGHTS into registers (96 VGPR) ----
    bf16x8 A1[4], A2[2], A3[8], A4[8], A5[2];
    #pragma unroll
    for (int jb = 0; jb < 4; ++jb) A1[jb] = *reinterpret_cast<const bf16x8*>(&w1[(jb*64 + lane)*8]);
    #pragma unroll
    for (int kb = 0; kb < 2; ++kb) A2[kb] = *reinterpret_cast<const bf16x8*>(&w2[(kb*64 + lane)*8]);
    #pragma unroll
    for (int i = 0; i < 8; ++i) {
        A3[i] = *reinterpret_cast<const bf16x8*>(&w3[(i*64 + lane)*8]);
        A4[i] = *reinterpret_cast<const bf16x8*>(&w4[(i*64 + lane)*8]);
    }
    #pragma unroll
    for (int kb = 0; kb < 2; ++kb) A5[kb] = *reinterpret_cast<const bf16x8*>(&w5[(kb*64 + lane)*8]);

    const int ntiles = (n + 127) >> 7;   // 128 points per block-tile (2 groups x 64)
    int t = blockIdx.x;
    if (t >= ntiles) return;

    // prefetch registers (next tile, both groups)
    int ppA_n, ppB_n; bool vA_n, vB_n;
    uint32_t fA0,fA1,fA2,fA3, fB0,fB1,fB2,fB3;
    float xA0,xA1,xA2, xB0,xB1,xB2, dA_n, dB_n;

    auto issue = [&](int tt) {
        const int prA = tt*128 + wv*16 + p16;
        const int prB = prA + 64;
        vA_n = (prA < n);  ppA_n = vA_n ? prA : (n - 1);
        vB_n = (prB < n);  ppB_n = vB_n ? prB : (n - 1);
        fA0 = feats_lm[(size_t)(4*quad+0)*n + ppA_n];
        fA1 = feats_lm[(size_t)(4*quad+1)*n + ppA_n];
        fA2 = feats_lm[(size_t)(4*quad+2)*n + ppA_n];
        fA3 = feats_lm[(size_t)(4*quad+3)*n + ppA_n];
        fB0 = feats_lm[(size_t)(4*quad+0)*n + ppB_n];
        fB1 = feats_lm[(size_t)(4*quad+1)*n + ppB_n];
        fB2 = feats_lm[(size_t)(4*quad+2)*n + ppB_n];
        fB3 = feats_lm[(size_t)(4*quad+3)*n + ppB_n];
        xA0 = xg[3*ppA_n+0]; xA1 = xg[3*ppA_n+1]; xA2 = xg[3*ppA_n+2];
        xB0 = xg[3*ppB_n+0]; xB1 = xg[3*ppB_n+1]; xB2 = xg[3*ppB_n+2];
        dA_n = dg[3*ppA_n + dc];
        dB_n = dg[3*ppB_n + dc];
    };

    issue(t);
    while (t < ntiles) {
        const int ppA = ppA_n, ppB = ppB_n;
        const bool vA = vA_n, vB = vB_n;
        const uint32_t a0 = fA0, a1 = fA1, a2 = fA2, a3 = fA3;
        const uint32_t b0 = fB0, b1v = fB1, b2v = fB2, b3v = fB3;
        const float cA0 = xA0, cA1 = xA1, cA2 = xA2;
        const float cB0 = xB0, cB1 = xB1, cB2 = xB2;
        const float dvA = dA_n, dvB = dB_n;

        const int t2 = t + gridDim.x;
        if (t2 < ntiles) issue(t2);

        const bool inA = (fabsf(cA0/3.0f) < 0.5f) && (fabsf(cA1/3.0f) < 0.5f) && (fabsf(cA2/3.0f) < 0.5f);
        const bool inB = (fabsf(cB0/3.0f) < 0.5f) && (fabsf(cB1/3.0f) < 0.5f) && (fabsf(cB2/3.0f) < 0.5f);

        // ---- L1: feats[32] -> hid[64], relu (two independent chains) ----
        union { int4 i; bf16x8 v; } buA, buB;
        buA.i.x = (int)a0; buA.i.y = (int)a1; buA.i.z = (int)a2; buA.i.w = (int)a3;
        buB.i.x = (int)b0; buB.i.y = (int)b1v; buB.i.z = (int)b2v; buB.i.w = (int)b3v;
        const bf16x8 bAa = buA.v, bAb = buB.v;
        #pragma unroll
        for (int jb = 0; jb < 4; ++jb) {
            const int j0 = jb*16 + quad*4;
            const f32x4 bias = *reinterpret_cast<const f32x4*>(&b1[j0]);
            f32x4 accA = __builtin_amdgcn_mfma_f32_16x16x32_bf16(A1[jb], bAa, bias, 0, 0, 0);
            f32x4 accB = __builtin_amdgcn_mfma_f32_16x16x32_bf16(A1[jb], bAb, bias, 0, 0, 0);
            uint2 sA, sB;
            sA.x = cvtpk(fmaxf(accA[0],0.f), fmaxf(accA[1],0.f));
            sA.y = cvtpk(fmaxf(accA[2],0.f), fmaxf(accA[3],0.f));
            sB.x = cvtpk(fmaxf(accB[0],0.f), fmaxf(accB[1],0.f));
            sB.y = cvtpk(fmaxf(accB[2],0.f), fmaxf(accB[3],0.f));
            *reinterpret_cast<uint2*>(&bufA[p16*ACT_STRIDE + j0]) = sA;
            *reinterpret_cast<uint2*>(&bufB[p16*ACT_STRIDE + j0]) = sB;
        }

        // ---- L2: hid[64] -> h16[16] (no relu); reads hoisted before writes ----
        {
            const bf16x8 fA0v = *reinterpret_cast<const bf16x8*>(&bufA[p16*ACT_STRIDE + quad*8]);
            const bf16x8 fA1v = *reinterpret_cast<const bf16x8*>(&bufA[p16*ACT_STRIDE + 32 + quad*8]);
            const bf16x8 fB0v = *reinterpret_cast<const bf16x8*>(&bufB[p16*ACT_STRIDE + quad*8]);
            const bf16x8 fB1v = *reinterpret_cast<const bf16x8*>(&bufB[p16*ACT_STRIDE + 32 + quad*8]);
            const f32x4 bias = *reinterpret_cast<const f32x4*>(&b2[quad*4]);
            f32x4 accA = __builtin_amdgcn_mfma_f32_16x16x32_bf16(A2[0], fA0v, bias, 0, 0, 0);
            f32x4 accB = __builtin_amdgcn_mfma_f32_16x16x32_bf16(A2[0], fB0v, bias, 0, 0, 0);
            accA = __builtin_amdgcn_mfma_f32_16x16x32_bf16(A2[1], fA1v, accA, 0, 0, 0);
            accB = __builtin_amdgcn_mfma_f32_16x16x32_bf16(A2[1], fB1v, accB, 0, 0, 0);
            if (quad == 0 && vA) out[(size_t)3*n + ppA] = inA ? __expf(accA[0]) : 0.0f;
            if (quad == 0 && vB) out[(size_t)3*n + ppB] = inB ? __expf(accB[0]) : 0.0f;
            uint2 sA, sB;
            sA.x = cvtpk(accA[0], accA[1]); sA.y = cvtpk(accA[2], accA[3]);
            sB.x = cvtpk(accB[0], accB[1]); sB.y = cvtpk(accB[2], accB[3]);
            *reinterpret_cast<uint2*>(&bufA[p16*ACT_STRIDE + quad*4]) = sA;
            *reinterpret_cast<uint2*>(&bufB[p16*ACT_STRIDE + quad*4]) = sB;
        }
        // pos-enc -> buf[p][16..42]; [43..63] stays stale-finite (w3 zeros cover it)
        if (quad < 3) {
            bufA[p16*ACT_STRIDE + 16 + quad] = bf1(dvA);
            bufB[p16*ACT_STRIDE + 16 + quad] = bf1(dvB);
            float argA = dvA, argB = dvB;
            #pragma unroll
            for (int f = 0; f < 4; ++f) {
                bufA[p16*ACT_STRIDE + 19 + 6*f + quad] = bf1(__sinf(argA));
                bufA[p16*ACT_STRIDE + 22 + 6*f + quad] = bf1(__cosf(argA));
                bufB[p16*ACT_STRIDE + 19 + 6*f + quad] = bf1(__sinf(argB));
                bufB[p16*ACT_STRIDE + 22 + 6*f + quad] = bf1(__cosf(argB));
                argA += argA; argB += argB;    // exact *2
            }
        }

        // ---- L3: cin[64(pad)] -> c1[64], relu ----
        {
            const bf16x8 fA0v = *reinterpret_cast<const bf16x8*>(&bufA[p16*ACT_STRIDE + quad*8]);
            const bf16x8 fA1v = *reinterpret_cast<const bf16x8*>(&bufA[p16*ACT_STRIDE + 32 + quad*8]);
            const bf16x8 fB0v = *reinterpret_cast<const bf16x8*>(&bufB[p16*ACT_STRIDE + quad*8]);
            const bf16x8 fB1v = *reinterpret_cast<const bf16x8*>(&bufB[p16*ACT_STRIDE + 32 + quad*8]);
            #pragma unroll
            for (int jb = 0; jb < 4; ++jb) {
                const int j0 = jb*16 + quad*4;
                const f32x4 bias = *reinterpret_cast<const f32x4*>(&b3[j0]);
                f32x4 accA = __builtin_amdgcn_mfma_f32_16x16x32_bf16(A3[jb*2+0], fA0v, bias, 0, 0, 0);
                f32x4 accB = __builtin_amdgcn_mfma_f32_16x16x32_bf16(A3[jb*2+0], fB0v, bias, 0, 0, 0);
                accA = __builtin_amdgcn_mfma_f32_16x16x32_bf16(A3[jb*2+1], fA1v, accA, 0, 0, 0);
                accB = __builtin_amdgcn_mfma_f32_16x16x32_bf16(A3[jb*2+1], fB1v, accB, 0, 0, 0);
                uint2 sA, sB;
                sA.x = cvtpk(fmaxf(accA[0],0.f), fmaxf(accA[1],0.f));
                sA.y = cvtpk(fmaxf(accA[2],0.f), fmaxf(accA[3],0.f));
                sB.x = cvtpk(fmaxf(accB[0],0.f), fmaxf(accB[1],0.f));
                sB.y = cvtpk(fmaxf(accB[2],0.f), fmaxf(accB[3],0.f));
                *reinterpret_cast<uint2*>(&bufA[p16*ACT_STRIDE + j0]) = sA;
                *reinterpret_cast<uint2*>(&bufB[p16*ACT_STRIDE + j0]) = sB;
            }
        }

        // ---- L4: c1[64] -> c2[64], relu ----
        {
            const bf16x8 fA0v = *reinterpret_cast<const bf16x8*>(&bufA[p16*ACT_STRIDE + quad*8]);
            const bf16x8 fA1v = *reinterpret_cast<const bf16x8*>(&bufA[p16*ACT_STRIDE + 32 + quad*8]);
            const bf16x8 fB0v = *reinterpret_cast<const bf16x8*>(&bufB[p16*ACT_STRIDE + quad*8]);
            const bf16x8 fB1v = *reinterpret_cast<const bf16x8*>(&bufB[p16*ACT_STRIDE + 32 + quad*8]);
            #pragma unroll
            for (int jb = 0; jb < 4; ++jb) {
                const int j0 = jb*16 + quad*4;
                const f32x4 bias = *reinterpret_cast<const f32x4*>(&b4[j0]);
                f32x4 accA = __builtin_amdgcn_mfma_f32_16x16x32_bf16(A4[jb*2+0], fA0v, bias, 0, 0, 0);
                f32x4 accB = __builtin_amdgcn_mfma_f32_16x16x32_bf16(A4[jb*2+0], fB0v, bias, 0, 0, 0);
                accA = __builtin_amdgcn_mfma_f32_16x16x32_bf16(A4[jb*2+1], fA1v, accA, 0, 0, 0);
                accB = __builtin_amdgcn_mfma_f32_16x16x32_bf16(A4[jb*2+1], fB1v, accB, 0, 0, 0);
                uint2 sA, sB;
                sA.x = cvtpk(fmaxf(accA[0],0.f), fmaxf(accA[1],0.f));
                sA.y = cvtpk(fmaxf(accA[2],0.f), fmaxf(accA[3],0.f));
                sB.x = cvtpk(fmaxf(accB[0],0.f), fmaxf(accB[1],0.f));
                sB.y = cvtpk(fmaxf(accB[2],0.f), fmaxf(accB[3],0.f));
                *reinterpret_cast<uint2*>(&bufA[p16*ACT_STRIDE + j0]) = sA;
                *reinterpret_cast<uint2*>(&bufB[p16*ACT_STRIDE + j0]) = sB;
            }
        }

        // ---- L5: c2[64] -> 16 (3 used), sigmoid, masked store ----
        {
            const bf16x8 fA0v = *reinterpret_cast<const bf16x8*>(&bufA[p16*ACT_STRIDE + quad*8]);
            const bf16x8 fA1v = *reinterpret_cast<const bf16x8*>(&bufA[p16*ACT_STRIDE + 32 + quad*8]);
            const bf16x8 fB0v = *reinterpret_cast<const bf16x8*>(&bufB[p16*ACT_STRIDE + quad*8]);
            const bf16x8 fB1v = *reinterpret_cast<const bf16x8*>(&bufB[p16*ACT_STRIDE + 32 + quad*8]);
            const f32x4 bias = *reinterpret_cast<const f32x4*>(&b5[quad*4]);
            f32x4 accA = __builtin_amdgcn_mfma_f32_16x16x32_bf16(A5[0], fA0v, bias, 0, 0, 0);
            f32x4 accB = __builtin_amdgcn_mfma_f32_16x16x32_bf16(A5[0], fB0v, bias, 0, 0, 0);
            accA = __builtin_amdgcn_mfma_f32_16x16x32_bf16(A5[1], fA1v, accA, 0, 0, 0);
            accB = __builtin_amdgcn_mfma_f32_16x16x32_bf16(A5[1], fB1v, accB, 0, 0, 0);
            if (quad == 0 && vA) {
                #pragma unroll
                for (int r = 0; r < 3; ++r) {
                    const float s = 1.0f / (1.0f + __expf(-accA[r]));
                    out[3*(size_t)ppA + r] = inA ? s : 0.0f;
                }
            }
            if (quad == 0 && vB) {
                #pragma unroll
                for (int r = 0; r < 3; ++r) {
                    const float s = 1.0f / (1.0f + __expf(-accB[r]));
                    out[3*(size_t)ppB + r] = inB ? s : 0.0f;
                }
            }
        }
        t = t2;
        // no barrier: act is wave-private; in-wave LDS ordering protects reuse
    }
}

extern "C" void kernel_launch(void* const* d_in, const int* in_sizes, int n_in,
                              void* d_out, int out_size, void* d_ws, size_t ws_size,
                              hipStream_t stream)
{
    const float* x   = (const float*)d_in[0];
    const float* d   = (const float*)d_in[1];
    const float* tb  = (const float*)d_in[2];
    const float* dW1 = (const float*)d_in[3];
    const float* db1 = (const float*)d_in[4];
    const float* dW2 = (const float*)d_in[5];
    const float* db2 = (const float*)d_in[6];
    const float* cW1 = (const float*)d_in[7];
    const float* cb1 = (const float*)d_in[8];
    const float* cW2 = (const float*)d_in[9];
    const float* cb2 = (const float*)d_in[10];
    const float* cW3 = (const float*)d_in[11];
    const float* cb3 = (const float*)d_in[12];
    float* out = (float*)d_out;

    const int n = in_sizes[0] / 3;              // N_PTS = 1M

    size_t off = 0;
    uint32_t* feats_lm = (uint32_t*)d_ws;                 off += (size_t)n * 16 * 4;
    uint32_t* tb16h    = (uint32_t*)((char*)d_ws + off);  off += (size_t)NHL * TS * 4;
    uint4*    quadbuf  = (uint4*)((char*)d_ws + off);     off += (size_t)QTOTAL * 16;
    const bool planA = (ws_size >= off);

    const unsigned tiles = (unsigned)((n + 255) / 256);
    const int ntiles = (n + 127) >> 7;
    const int nblk = (ntiles < 512) ? ntiles : 512;       // 2 blocks/CU (VGPR-bound)

    if (planA) {
        {
            const int npairs = NHL * (int)TS;
            hipLaunchKernelGGL(cvt_tables_h, dim3((npairs + 255) / 256), dim3(256), 0, stream,
                               (const float2*)tb + 5 * (size_t)TS, tb16h, npairs);
        }
        hipLaunchKernelGGL(build_quad, dim3((QTOTAL + 255) / 256), dim3(256), 0, stream,
                           (const float2*)tb, quadbuf);
        hipLaunchKernelGGL(ngp_encode_lm, dim3(tiles * 16), dim3(256), 0, stream,
                           x, tb16h, quadbuf, feats_lm, n, tiles);
    } else {
        hipLaunchKernelGGL(ngp_encode_f32, dim3(tiles * 16), dim3(256), 0, stream,
                           x, (const float2*)tb, feats_lm, n, tiles);
    }
    hipLaunchKernelGGL(ngp_mlp_mfma, dim3(nblk), dim3(256), 0, stream,
                       x, d, feats_lm, dW1, db1, dW2, db2,
                       cW1, cb1, cW2, cb2, cW3, cb3, out, n);
}